// Round 4
// baseline (350.936 us; speedup 1.0000x reference)
//
#include <hip/hip_runtime.h>

#define N_NODES 200000
#define N_EDGES 3200000
#define N_GRAPHS 1024
#define HD 16
#define ALPHA_ 0.2f

#define BNODES 512                 // nodes per bucket (dst >> 9)
#define NBUCK 391                  // ceil(N_NODES/512)
#define CHUNKA 8192                // edges per pass block (512 thr x 4 x int4)
#define NBLKA 391                  // ceil(N_EDGES/8192)
#define CAP 9216                   // padded bucket capacity (mean 8192, sigma~90, +11 sigma)

typedef unsigned long long u64;

// ---------- single-pass bucketing: per-block LDS hist -> one global atomic per
// (block,bucket) reserves a contiguous run in the PADDED bucket region ----------
// entry = (ea:32 | dlow:9 | src:18)
__global__ __launch_bounds__(512) void bucket_kernel(const int* __restrict__ src,
                                                     const int* __restrict__ dst,
                                                     const float* __restrict__ ea,
                                                     int* __restrict__ gcursor,
                                                     u64* __restrict__ bucketedP) {
    __shared__ int hist[NBUCK];
    __shared__ int cursor[NBUCK];
    int t = threadIdx.x;
    for (int i = t; i < NBUCK; i += 512) hist[i] = 0;
    __syncthreads();
    int e0 = blockIdx.x * CHUNKA;
    int e1 = min(e0 + CHUNKA, N_EDGES);
#pragma unroll
    for (int k = 0; k < 4; ++k) {
        int e = e0 + (k << 11) + (t << 2);
        if (e < e1) {   // e, e1 multiples of 4 -> full int4 valid
            int4 d4 = *(const int4*)(dst + e);
            atomicAdd(&hist[d4.x >> 9], 1);
            atomicAdd(&hist[d4.y >> 9], 1);
            atomicAdd(&hist[d4.z >> 9], 1);
            atomicAdd(&hist[d4.w >> 9], 1);
        }
    }
    __syncthreads();
    for (int u = t; u < NBUCK; u += 512) {
        int c = hist[u];
        cursor[u] = (c > 0) ? (u * CAP + atomicAdd(&gcursor[u], c)) : 0;
    }
    __syncthreads();
#pragma unroll
    for (int k = 0; k < 4; ++k) {
        int e = e0 + (k << 11) + (t << 2);
        if (e < e1) {   // dst chunk L1/L2-hot from pass 1
            int4   d4 = *(const int4*)(dst + e);
            int4   s4 = *(const int4*)(src + e);
            float4 a4 = *(const float4*)(ea + e);
            int p0 = atomicAdd(&cursor[d4.x >> 9], 1);
            int p1 = atomicAdd(&cursor[d4.y >> 9], 1);
            int p2 = atomicAdd(&cursor[d4.z >> 9], 1);
            int p3 = atomicAdd(&cursor[d4.w >> 9], 1);
            bucketedP[p0] = ((u64)__float_as_uint(a4.x) << 32) | (unsigned)(s4.x | ((d4.x & 511) << 18));
            bucketedP[p1] = ((u64)__float_as_uint(a4.y) << 32) | (unsigned)(s4.y | ((d4.y & 511) << 18));
            bucketedP[p2] = ((u64)__float_as_uint(a4.z) << 32) | (unsigned)(s4.z | ((d4.z & 511) << 18));
            bucketedP[p3] = ((u64)__float_as_uint(a4.w) << 32) | (unsigned)(s4.w | ((d4.w & 511) << 18));
        }
    }
}

// exclusive scan over bucket counts (gcursor) -> compact bucket starts
__global__ __launch_bounds__(256) void scanB_kernel(const int* __restrict__ gcursor,
                                                    int* __restrict__ bstart) {
    __shared__ int s[256];
    int t = threadIdx.x;
    int v[2];
    int sum = 0;
#pragma unroll
    for (int i = 0; i < 2; ++i) {
        int j = t * 2 + i;
        v[i] = (j < NBUCK) ? gcursor[j] : 0;
        sum += v[i];
    }
    s[t] = sum;
    __syncthreads();
    for (int off = 1; off < 256; off <<= 1) {
        int x = (t >= off) ? s[t - off] : 0;
        __syncthreads();
        s[t] += x;
        __syncthreads();
    }
    int run = s[t] - sum;
#pragma unroll
    for (int i = 0; i < 2; ++i) {
        int j = t * 2 + i;
        if (j < NBUCK) bstart[j] = run;
        run += v[i];
    }
    if (t == 255) bstart[NBUCK] = s[255];
}

// radix pass 2: in-bucket counting sort by dlow (9b, int LDS atomics) + fused
// per-node weighted degree -> dinv, dx = {dinv, dinv*x}.
// reads PADDED bucket region, writes COMPACT sorted/nodeoff.
__global__ __launch_bounds__(1024) void sortd_kernel(const u64* __restrict__ bucketedP,
                                                     const int* __restrict__ gcursor,
                                                     const int* __restrict__ bstart,
                                                     const float* __restrict__ x,
                                                     u64* __restrict__ sorted,
                                                     int* __restrict__ nodeoff,
                                                     float* __restrict__ dinv,
                                                     float2* __restrict__ dx) {
    __shared__ int hist[512];
    __shared__ int s[512];
    __shared__ int cur[512];
    __shared__ float fdeg[1024];
    int u = blockIdx.x, t = threadIdx.x;
    if (t < 512) hist[t] = 0;
    __syncthreads();
    int m = gcursor[u];                  // bucket count
    const u64* bp = bucketedP + (size_t)u * CAP;
    int b0 = bstart[u];                  // compact output base
    for (int i = t; i < m; i += 1024)
        atomicAdd(&hist[(int)((bp[i] >> 18) & 511u)], 1);
    __syncthreads();
    int c = (t < 512) ? hist[t] : 0;
    if (t < 512) s[t] = c;
    __syncthreads();
    for (int off = 1; off < 512; off <<= 1) {
        int v = (t >= off && t < 512) ? s[t - off] : 0;
        __syncthreads();
        if (t < 512) s[t] += v;
        __syncthreads();
    }
    if (t < 512) {
        int loc = b0 + s[t] - c;   // exclusive
        cur[t] = loc;
        int n = u * BNODES + t;
        if (n < N_NODES) nodeoff[n] = loc;
    }
    __syncthreads();
    for (int i = t; i < m; i += 1024) {
        u64 ent = bp[i];
        int pos = atomicAdd(&cur[(int)((ent >> 18) & 511u)], 1);
        sorted[pos] = ent;
    }
    __syncthreads();
    // 2 threads/node weighted degree over own contiguous range (L1/L2-hot)
    {
        int idx = t & 511, half = t >> 9;
        int cc = hist[idx];
        int lloc = b0 + s[idx] - cc;
        float sum = 0.f;
        for (int k = half; k < cc; k += 2)
            sum += __uint_as_float((unsigned)(sorted[lloc + k] >> 32));
        fdeg[t] = sum;
    }
    __syncthreads();
    if (t < 512) {
        int n = u * BNODES + t;
        if (n < N_NODES) {
            float tot = fdeg[t] + fdeg[t + 512];
            float dn = rsqrtf(tot + 1.0f);
            dinv[n] = dn;
            dx[n] = make_float2(dn, dn * x[n]);
        }
    }
}

// layer 0: 4 threads/node (stride-4, 2 gathers in flight), 2-level shfl combine
__global__ __launch_bounds__(256) void agg0_kernel(const u64* __restrict__ sorted,
                                                   const int* __restrict__ nodeoff,
                                                   const float2* __restrict__ dx,
                                                   float2* __restrict__ db0,
                                                   float* __restrict__ s1v) {
    int t = threadIdx.x;
    int n = blockIdx.x * 64 + (t >> 2);   // 3125 * 64 = 200000 exactly
    int h = t & 3;
    float acc = 0.f, wsum = 0.f;
    {
        int e0 = nodeoff[n];
        int e1 = (n < N_NODES - 1) ? nodeoff[n + 1] : N_EDGES;
        int i = e0 + h;
        for (; i + 4 < e1; i += 8) {
            u64 en0 = sorted[i], en1 = sorted[i + 4];
            float2 g0 = dx[(int)(en0 & 0x3ffffu)];
            float2 g1 = dx[(int)(en1 & 0x3ffffu)];
            float a0 = __uint_as_float((unsigned)(en0 >> 32));
            float a1 = __uint_as_float((unsigned)(en1 >> 32));
            acc  += a0 * g0.y + a1 * g1.y;
            wsum += a0 * g0.x + a1 * g1.x;
        }
        if (i < e1) {
            u64 en = sorted[i];
            float2 g = dx[(int)(en & 0x3ffffu)];
            float a = __uint_as_float((unsigned)(en >> 32));
            acc += a * g.y;
            wsum += a * g.x;
        }
    }
    acc += __shfl_xor(acc, 1);
    wsum += __shfl_xor(wsum, 1);
    acc += __shfl_xor(acc, 2);
    wsum += __shfl_xor(wsum, 2);
    if (h == 0) {
        float2 d2 = dx[n];
        float dn = d2.x;
        float base0 = dn * acc + dn * d2.y;     // + dn^2 * x[n]
        db0[n] = make_float2(dn, base0);
        s1v[n] = dn * wsum + dn * dn;
    }
}

// layer 1: 2 threads/node edge phase (q[16] partials, 4 gathers in flight),
// then 16-lane epilogue: v2 = q@M + c*m2 + cb1 ; h2hat = dinv*(relu(v2)@lw1 + lb1)
__global__ __launch_bounds__(256) void agg1_kernel(const u64* __restrict__ sorted,
                                                   const int* __restrict__ nodeoff,
                                                   const float2* __restrict__ db0,
                                                   const float* __restrict__ s1v,
                                                   const float* __restrict__ cw0,
                                                   const float* __restrict__ cb0,
                                                   const float* __restrict__ lw0,
                                                   const float* __restrict__ lb0,
                                                   const float* __restrict__ cwr0,
                                                   const float* __restrict__ cb1,
                                                   const float* __restrict__ lw1,
                                                   const float* __restrict__ lb1,
                                                   float* __restrict__ h2hat) {
    __shared__ float sq[128 * 20];   // per node: q[16], c, dn, pad2  (10 KB)
    __shared__ float sa2[256];       // wave-local relu scratch
    __shared__ float sM[256];        // M = lw0 @ cwr0
    __shared__ float sm2[16];        // m2 = lb0 @ cwr0
    int t = threadIdx.x;
    int j = t & 15;
    {   // fused prep
        int kk = t >> 4;
        float accM = 0.f;
#pragma unroll
        for (int xx = 0; xx < 16; ++xx) accM += lw0[kk * 16 + xx] * cwr0[xx * 16 + j];
        sM[t] = accM;
        if (t < 16) {
            float a2 = 0.f;
#pragma unroll
            for (int xx = 0; xx < 16; ++xx) a2 += lb0[xx] * cwr0[xx * 16 + t];
            sm2[t] = a2;
        }
    }
    __syncthreads();
    float cwr[16], cbr[16];
#pragma unroll
    for (int k = 0; k < 16; ++k) { cwr[k] = cw0[k]; cbr[k] = cb0[k]; }

    int n = blockIdx.x * 128 + (t >> 1);
    int h = t & 1;
    float q[16];
#pragma unroll
    for (int k = 0; k < 16; ++k) q[k] = 0.f;
    if (n < N_NODES) {
        int e0 = nodeoff[n];
        int e1 = (n < N_NODES - 1) ? nodeoff[n + 1] : N_EDGES;
        int i = e0 + h;
        for (; i + 6 < e1; i += 8) {
            u64 en0 = sorted[i],     en1 = sorted[i + 2];
            u64 en2 = sorted[i + 4], en3 = sorted[i + 6];
            float2 g0 = db0[(int)(en0 & 0x3ffffu)];
            float2 g1 = db0[(int)(en1 & 0x3ffffu)];
            float2 g2 = db0[(int)(en2 & 0x3ffffu)];
            float2 g3 = db0[(int)(en3 & 0x3ffffu)];
            float a0 = __uint_as_float((unsigned)(en0 >> 32)) * g0.x;  // ea*dinv[s]
            float a1 = __uint_as_float((unsigned)(en1 >> 32)) * g1.x;
            float a2 = __uint_as_float((unsigned)(en2 >> 32)) * g2.x;
            float a3 = __uint_as_float((unsigned)(en3 >> 32)) * g3.x;
#pragma unroll
            for (int k = 0; k < 16; ++k)
                q[k] += a0 * fmaxf(g0.y * cwr[k] + cbr[k], 0.f)
                      + a1 * fmaxf(g1.y * cwr[k] + cbr[k], 0.f)
                      + a2 * fmaxf(g2.y * cwr[k] + cbr[k], 0.f)
                      + a3 * fmaxf(g3.y * cwr[k] + cbr[k], 0.f);
        }
        for (; i < e1; i += 2) {
            u64 en = sorted[i];
            float2 g = db0[(int)(en & 0x3ffffu)];
            float a = __uint_as_float((unsigned)(en >> 32)) * g.x;
#pragma unroll
            for (int k = 0; k < 16; ++k)
                q[k] += a * fmaxf(g.y * cwr[k] + cbr[k], 0.f);
        }
    }
    // combine halves (lane pairs 2k/2k+1, in-wave)
#pragma unroll
    for (int k = 0; k < 16; ++k) q[k] += __shfl_xor(q[k], 1);
    float dn = 0.f, cval = 0.f;
    if (n < N_NODES) {
        float2 self = db0[n];
        dn = self.x;
        float ds = dn * dn;
#pragma unroll
        for (int k = 0; k < 16; ++k)
            q[k] = dn * q[k] + ds * fmaxf(self.y * cwr[k] + cbr[k], 0.f);
        cval = s1v[n];
    }
    if (h == 0) {
        float* row = sq + (t >> 1) * 20;
#pragma unroll
        for (int k = 0; k < 16; k += 4)
            *(float4*)(row + k) = make_float4(q[k], q[k + 1], q[k + 2], q[k + 3]);
        row[16] = cval;
        row[17] = dn;
    }
    __syncthreads();
    // epilogue weights loaded post edge phase (lower edge-phase VGPR)
    float Mc[16], W1c[16];
#pragma unroll
    for (int k = 0; k < 16; ++k) { Mc[k] = sM[k * 16 + j]; W1c[k] = lw1[k * 16 + j]; }
    float m2j = sm2[j], cb1j = cb1[j], lb1j = lb1[j];
    int g = t >> 4;
    float* ar = sa2 + g * 16;
    for (int it = 0; it < 8; ++it) {
        int nl = g * 8 + it;
        const float* r = sq + nl * 20;
        float4 q0 = *(const float4*)(r);
        float4 q1 = *(const float4*)(r + 4);
        float4 q2 = *(const float4*)(r + 8);
        float4 q3 = *(const float4*)(r + 12);
        float c2 = r[16], dn2 = r[17];
        float v2 = c2 * m2j + cb1j;
        v2 += q0.x * Mc[0] + q0.y * Mc[1] + q0.z * Mc[2] + q0.w * Mc[3];
        v2 += q1.x * Mc[4] + q1.y * Mc[5] + q1.z * Mc[6] + q1.w * Mc[7];
        v2 += q2.x * Mc[8] + q2.y * Mc[9] + q2.z * Mc[10] + q2.w * Mc[11];
        v2 += q3.x * Mc[12] + q3.y * Mc[13] + q3.z * Mc[14] + q3.w * Mc[15];
        ar[j] = fmaxf(v2, 0.f);          // wave-local
        float o = lb1j;
#pragma unroll
        for (int k = 0; k < 16; ++k) o += ar[k] * W1c[k];
        int n2 = blockIdx.x * 128 + nl;
        if (n2 < N_NODES) h2hat[(size_t)n2 * 16 + j] = dn2 * o;
    }
}

// layer 2: PINNED at random-64B-line fetch ceiling (67.5 µs across 3 configs,
// R9/R12/R14; R2-fusion attempt regressed it to 94 via VGPR 36->48, occupancy
// 60->41 — reverted verbatim, do not add state to this kernel).
__global__ __launch_bounds__(256) void agg2_kernel(const u64* __restrict__ sorted,
                                                   const int* __restrict__ nodeoff,
                                                   const float* __restrict__ h2hat,
                                                   const float* __restrict__ dinv,
                                                   const float* __restrict__ cwr1,
                                                   const float* __restrict__ cb2,
                                                   const float* __restrict__ lw2,
                                                   const float* __restrict__ lb2,
                                                   float* __restrict__ h3) {
    __shared__ float sz[256];   // per (group, j) — wave-local roundtrip
    int t = threadIdx.x, j = t & 15, g = t >> 4;
    float W1c[16], W2c[16];
#pragma unroll
    for (int k = 0; k < 16; ++k) { W1c[k] = cwr1[k * 16 + j]; W2c[k] = lw2[k * 16 + j]; }
    float cb2j = cb2[j], lb2j = lb2[j];
    const float* zr = sz + g * 16;
    int nbase = blockIdx.x * 64 + g * 4;     // 3125 * 64 = 200000 exactly
#pragma unroll
    for (int it = 0; it < 4; ++it) {
        int n = nbase + it;
        int e0 = nodeoff[n];
        int e1 = (n < N_NODES - 1) ? nodeoff[n + 1] : N_EDGES;
        float q = 0.f;
        int i = e0;
        for (; i + 8 <= e1; i += 8) {
            u64 en0 = sorted[i],     en1 = sorted[i + 1], en2 = sorted[i + 2], en3 = sorted[i + 3];
            u64 en4 = sorted[i + 4], en5 = sorted[i + 5], en6 = sorted[i + 6], en7 = sorted[i + 7];
            float g0 = h2hat[(size_t)(en0 & 0x3ffffu) * 16 + j];
            float g1 = h2hat[(size_t)(en1 & 0x3ffffu) * 16 + j];
            float g2 = h2hat[(size_t)(en2 & 0x3ffffu) * 16 + j];
            float g3 = h2hat[(size_t)(en3 & 0x3ffffu) * 16 + j];
            float g4 = h2hat[(size_t)(en4 & 0x3ffffu) * 16 + j];
            float g5 = h2hat[(size_t)(en5 & 0x3ffffu) * 16 + j];
            float g6 = h2hat[(size_t)(en6 & 0x3ffffu) * 16 + j];
            float g7 = h2hat[(size_t)(en7 & 0x3ffffu) * 16 + j];
            q += __uint_as_float((unsigned)(en0 >> 32)) * g0
               + __uint_as_float((unsigned)(en1 >> 32)) * g1
               + __uint_as_float((unsigned)(en2 >> 32)) * g2
               + __uint_as_float((unsigned)(en3 >> 32)) * g3
               + __uint_as_float((unsigned)(en4 >> 32)) * g4
               + __uint_as_float((unsigned)(en5 >> 32)) * g5
               + __uint_as_float((unsigned)(en6 >> 32)) * g6
               + __uint_as_float((unsigned)(en7 >> 32)) * g7;
        }
        for (; i < e1; ++i) {
            u64 en = sorted[i];
            q += __uint_as_float((unsigned)(en >> 32)) * h2hat[(size_t)(en & 0x3ffffu) * 16 + j];
        }
        float dn = dinv[n];
        float z = dn * (q + h2hat[(size_t)n * 16 + j]);   // + dn^2 * h2[n]
        sz[t] = z;                                        // wave-local
        float v = cb2j;
#pragma unroll
        for (int k = 0; k < 16; ++k) v += zr[k] * W1c[k];
        float a = fmaxf(v, 0.f);
        sz[t] = a;                                        // wave-local overwrite
        float o = lb2j;
#pragma unroll
        for (int k = 0; k < 16; ++k) o += zr[k] * W2c[k];
        h3[(size_t)n * 16 + j] = o;
    }
}

// fused attention-pool + final MLP: one 64-thread wave per graph.
__global__ __launch_bounds__(64) void poolfinal_kernel(const float* __restrict__ h3,
                                                       const int* __restrict__ batch,
                                                       const float* __restrict__ w1,
                                                       const float* __restrict__ b1,
                                                       const float* __restrict__ w2,
                                                       const float* __restrict__ b2,
                                                       const float* __restrict__ w3,
                                                       const float* __restrict__ b3,
                                                       float* __restrict__ out) {
    int g = blockIdx.x;
    int t = threadIdx.x;
    int j = t & 15, sg = t >> 4;
    __shared__ int range[2];
    if (t < 2) {
        int target = g + t;          // lower_bound(batch, g) / lower_bound(batch, g+1)
        int lo = 0, hi = N_NODES;
        while (lo < hi) {
            int mid = (lo + hi) >> 1;
            if (batch[mid] < target) lo = mid + 1; else hi = mid;
        }
        range[t] = lo;
    }
    __syncthreads();
    int n0 = range[0], n1 = range[1];
    float accn = 0.f, accd = 0.f;
    for (int n = n0 + sg; n < n1; n += 4) {
        float v = h3[(size_t)n * 16 + j];
        float e = __expf(ALPHA_ * v);
        accn += v * e;
        accd += e;
    }
    accn += __shfl_xor(accn, 16);
    accd += __shfl_xor(accd, 16);
    accn += __shfl_xor(accn, 32);
    accd += __shfl_xor(accd, 32);
    __shared__ float sp[16], st1[16], st2[16];
    if (t < 16) sp[j] = (accd > 0.f) ? accn / accd : 0.f;
    __syncthreads();
    if (t < 16) {
        float acc = b1[j];
#pragma unroll
        for (int k = 0; k < 16; ++k) acc += sp[k] * w1[k * 16 + j];
        st1[j] = fmaxf(acc, 0.f);
    }
    __syncthreads();
    if (t < 16) {
        float acc = b2[j];
#pragma unroll
        for (int k = 0; k < 16; ++k) acc += st1[k] * w2[k * 16 + j];
        st2[j] = fmaxf(acc, 0.f);
    }
    __syncthreads();
    if (t == 0) {
        float o = b3[0];
#pragma unroll
        for (int k = 0; k < 16; ++k) o += st2[k] * w3[k];
        out[g] = o;
    }
}

extern "C" void kernel_launch(void* const* d_in, const int* in_sizes, int n_in,
                              void* d_out, int out_size, void* d_ws, size_t ws_size,
                              hipStream_t stream) {
    const float* x   = (const float*)d_in[0];
    const int*   ei  = (const int*)d_in[1];
    const int*   src = ei;
    const int*   dst = ei + N_EDGES;
    const int*   batch = (const int*)d_in[2];
    const float* ea  = (const float*)d_in[3];
    const float* cw0 = (const float*)d_in[4];
    const float* cwr = (const float*)d_in[5];
    const float* cb  = (const float*)d_in[6];
    const float* lw  = (const float*)d_in[7];
    const float* lb  = (const float*)d_in[8];
    const float* w1  = (const float*)d_in[9];
    const float* b1  = (const float*)d_in[10];
    const float* w2  = (const float*)d_in[11];
    const float* b2  = (const float*)d_in[12];
    const float* w3  = (const float*)d_in[13];
    const float* b3  = (const float*)d_in[14];
    float* out = (float*)d_out;

    // workspace layout (4-byte units), total ~15.0M floats (< prior 16.3M peak)
    float* ws      = (float*)d_ws;
    float* dinv    = ws;                                   // 200000
    float* s1v     = ws + 200000;                          // 200000
    float2* db0    = (float2*)(ws + 400000);               // 400000 floats
    int*   bstart  = (int*)(ws + 800000);                  // 392 (pad 784)
    int*   nodeoff = bstart + 784;                         // 200010
    int*   gcursor = nodeoff + 200010;                     // 392
    float2* dx     = (float2*)(ws + 1001186);              // 400000 floats (even offset)
    u64* bucketedP = (u64*)(ws + 1401186);                 // 391*9216 u64 = 7206912 floats (even)
    u64* sorted    = (u64*)(ws + 8608098);                 // 3.2M u64 = 6400000 floats (even)
    float* h2hat   = (float*)bucketedP;                    // alias: free after sortd (3.2M floats)
    float* h3      = h2hat + (size_t)N_NODES * HD;         // alias (within bucketedP region)

    hipMemsetAsync(gcursor, 0, (size_t)392 * sizeof(int), stream);

    // single-pass bucketing (global atomic reservation, padded buckets)
    bucket_kernel<<<NBLKA, 512, 0, stream>>>(src, dst, ea, gcursor, bucketedP);
    // compact bucket starts
    scanB_kernel<<<1, 256, 0, stream>>>(gcursor, bstart);
    // in-bucket counting sort + dinv/dx
    sortd_kernel<<<NBUCK, 1024, 0, stream>>>(bucketedP, gcursor, bstart, x, sorted, nodeoff, dinv, dx);

    // layer 0 (4 threads/node) -> db0={dinv,base0}, s1
    agg0_kernel<<<3125, 256, 0, stream>>>(sorted, nodeoff, dx, db0, s1v);
    // layer 1 (2 threads/node, 4-wide MLP + fused prep + 2-stage epilogue) -> h2hat
    agg1_kernel<<<1563, 256, 0, stream>>>(sorted, nodeoff, db0, s1v,
                                          cw0, cb, lw, lb,
                                          cwr, cb + 16, lw + 256, lb + 16, h2hat);
    // layer 2 (unroll-8 gathers) -> h3
    agg2_kernel<<<3125, 256, 0, stream>>>(sorted, nodeoff, h2hat, dinv,
                                          cwr + 256, cb + 32, lw + 512, lb + 32, h3);

    // fused attention pooling + final MLP (one wave per graph)
    poolfinal_kernel<<<N_GRAPHS, 64, 0, stream>>>(h3, batch, w1, b1, w2, b2, w3, b3, out);
}

// Round 5
// 321.904 us; speedup vs baseline: 1.0902x; 1.0902x over previous
//
#include <hip/hip_runtime.h>

#define N_NODES 200000
#define N_EDGES 3200000
#define N_GRAPHS 1024
#define HD 16
#define ALPHA_ 0.2f

#define BNODES 512                 // nodes per bucket (dst >> 9)
#define NBUCK 391                  // ceil(N_NODES/512)
#define CHUNKA 8192                // edges per pass block (512 thr x 4 x int4)
#define NBLKA 391                  // ceil(N_EDGES/8192)
#define CAP 9216                   // padded bucket capacity (mean 8192, sigma~90, +11 sigma)

typedef unsigned long long u64;

// ---------- single-pass bucketing: per-block LDS hist -> one global atomic per
// (block,bucket) reserves a contiguous run in the PADDED bucket region ----------
// entry = (ea:32 | dlow:9 | src:18)
__global__ __launch_bounds__(512) void bucket_kernel(const int* __restrict__ src,
                                                     const int* __restrict__ dst,
                                                     const float* __restrict__ ea,
                                                     int* __restrict__ gcursor,
                                                     u64* __restrict__ bucketedP) {
    __shared__ int hist[NBUCK];
    __shared__ int cursor[NBUCK];
    int t = threadIdx.x;
    for (int i = t; i < NBUCK; i += 512) hist[i] = 0;
    __syncthreads();
    int e0 = blockIdx.x * CHUNKA;
    int e1 = min(e0 + CHUNKA, N_EDGES);
#pragma unroll
    for (int k = 0; k < 4; ++k) {
        int e = e0 + (k << 11) + (t << 2);
        if (e < e1) {   // e, e1 multiples of 4 -> full int4 valid
            int4 d4 = *(const int4*)(dst + e);
            atomicAdd(&hist[d4.x >> 9], 1);
            atomicAdd(&hist[d4.y >> 9], 1);
            atomicAdd(&hist[d4.z >> 9], 1);
            atomicAdd(&hist[d4.w >> 9], 1);
        }
    }
    __syncthreads();
    for (int u = t; u < NBUCK; u += 512) {
        int c = hist[u];
        cursor[u] = (c > 0) ? (u * CAP + atomicAdd(&gcursor[u], c)) : 0;
    }
    __syncthreads();
#pragma unroll
    for (int k = 0; k < 4; ++k) {
        int e = e0 + (k << 11) + (t << 2);
        if (e < e1) {   // dst chunk L1/L2-hot from pass 1
            int4   d4 = *(const int4*)(dst + e);
            int4   s4 = *(const int4*)(src + e);
            float4 a4 = *(const float4*)(ea + e);
            int p0 = atomicAdd(&cursor[d4.x >> 9], 1);
            int p1 = atomicAdd(&cursor[d4.y >> 9], 1);
            int p2 = atomicAdd(&cursor[d4.z >> 9], 1);
            int p3 = atomicAdd(&cursor[d4.w >> 9], 1);
            bucketedP[p0] = ((u64)__float_as_uint(a4.x) << 32) | (unsigned)(s4.x | ((d4.x & 511) << 18));
            bucketedP[p1] = ((u64)__float_as_uint(a4.y) << 32) | (unsigned)(s4.y | ((d4.y & 511) << 18));
            bucketedP[p2] = ((u64)__float_as_uint(a4.z) << 32) | (unsigned)(s4.z | ((d4.z & 511) << 18));
            bucketedP[p3] = ((u64)__float_as_uint(a4.w) << 32) | (unsigned)(s4.w | ((d4.w & 511) << 18));
        }
    }
}

// exclusive scan over bucket counts (gcursor) -> compact bucket starts
__global__ __launch_bounds__(256) void scanB_kernel(const int* __restrict__ gcursor,
                                                    int* __restrict__ bstart) {
    __shared__ int s[256];
    int t = threadIdx.x;
    int v[2];
    int sum = 0;
#pragma unroll
    for (int i = 0; i < 2; ++i) {
        int j = t * 2 + i;
        v[i] = (j < NBUCK) ? gcursor[j] : 0;
        sum += v[i];
    }
    s[t] = sum;
    __syncthreads();
    for (int off = 1; off < 256; off <<= 1) {
        int x = (t >= off) ? s[t - off] : 0;
        __syncthreads();
        s[t] += x;
        __syncthreads();
    }
    int run = s[t] - sum;
#pragma unroll
    for (int i = 0; i < 2; ++i) {
        int j = t * 2 + i;
        if (j < NBUCK) bstart[j] = run;
        run += v[i];
    }
    if (t == 255) bstart[NBUCK] = s[255];
}

// radix pass 2: in-bucket counting sort by dlow (9b, int LDS atomics) + fused
// per-node weighted degree -> dinv, dx = {dinv, dinv*x}.
// reads PADDED bucket region, writes COMPACT sorted/nodeoff.
__global__ __launch_bounds__(1024) void sortd_kernel(const u64* __restrict__ bucketedP,
                                                     const int* __restrict__ gcursor,
                                                     const int* __restrict__ bstart,
                                                     const float* __restrict__ x,
                                                     u64* __restrict__ sorted,
                                                     int* __restrict__ nodeoff,
                                                     float* __restrict__ dinv,
                                                     float2* __restrict__ dx) {
    __shared__ int hist[512];
    __shared__ int s[512];
    __shared__ int cur[512];
    __shared__ float fdeg[1024];
    int u = blockIdx.x, t = threadIdx.x;
    if (t < 512) hist[t] = 0;
    __syncthreads();
    int m = gcursor[u];                  // bucket count
    const u64* bp = bucketedP + (size_t)u * CAP;
    int b0 = bstart[u];                  // compact output base
    for (int i = t; i < m; i += 1024)
        atomicAdd(&hist[(int)((bp[i] >> 18) & 511u)], 1);
    __syncthreads();
    int c = (t < 512) ? hist[t] : 0;
    if (t < 512) s[t] = c;
    __syncthreads();
    for (int off = 1; off < 512; off <<= 1) {
        int v = (t >= off && t < 512) ? s[t - off] : 0;
        __syncthreads();
        if (t < 512) s[t] += v;
        __syncthreads();
    }
    if (t < 512) {
        int loc = b0 + s[t] - c;   // exclusive
        cur[t] = loc;
        int n = u * BNODES + t;
        if (n < N_NODES) nodeoff[n] = loc;
    }
    __syncthreads();
    for (int i = t; i < m; i += 1024) {
        u64 ent = bp[i];
        int pos = atomicAdd(&cur[(int)((ent >> 18) & 511u)], 1);
        sorted[pos] = ent;
    }
    __syncthreads();
    // 2 threads/node weighted degree over own contiguous range (L1/L2-hot)
    {
        int idx = t & 511, half = t >> 9;
        int cc = hist[idx];
        int lloc = b0 + s[idx] - cc;
        float sum = 0.f;
        for (int k = half; k < cc; k += 2)
            sum += __uint_as_float((unsigned)(sorted[lloc + k] >> 32));
        fdeg[t] = sum;
    }
    __syncthreads();
    if (t < 512) {
        int n = u * BNODES + t;
        if (n < N_NODES) {
            float tot = fdeg[t] + fdeg[t + 512];
            float dn = rsqrtf(tot + 1.0f);
            dinv[n] = dn;
            dx[n] = make_float2(dn, dn * x[n]);
        }
    }
}

// layer 0: 4 threads/node (stride-4, 2 gathers in flight), 2-level shfl combine
__global__ __launch_bounds__(256) void agg0_kernel(const u64* __restrict__ sorted,
                                                   const int* __restrict__ nodeoff,
                                                   const float2* __restrict__ dx,
                                                   float2* __restrict__ db0,
                                                   float* __restrict__ s1v) {
    int t = threadIdx.x;
    int n = blockIdx.x * 64 + (t >> 2);   // 3125 * 64 = 200000 exactly
    int h = t & 3;
    float acc = 0.f, wsum = 0.f;
    {
        int e0 = nodeoff[n];
        int e1 = (n < N_NODES - 1) ? nodeoff[n + 1] : N_EDGES;
        int i = e0 + h;
        for (; i + 4 < e1; i += 8) {
            u64 en0 = sorted[i], en1 = sorted[i + 4];
            float2 g0 = dx[(int)(en0 & 0x3ffffu)];
            float2 g1 = dx[(int)(en1 & 0x3ffffu)];
            float a0 = __uint_as_float((unsigned)(en0 >> 32));
            float a1 = __uint_as_float((unsigned)(en1 >> 32));
            acc  += a0 * g0.y + a1 * g1.y;
            wsum += a0 * g0.x + a1 * g1.x;
        }
        if (i < e1) {
            u64 en = sorted[i];
            float2 g = dx[(int)(en & 0x3ffffu)];
            float a = __uint_as_float((unsigned)(en >> 32));
            acc += a * g.y;
            wsum += a * g.x;
        }
    }
    acc += __shfl_xor(acc, 1);
    wsum += __shfl_xor(wsum, 1);
    acc += __shfl_xor(acc, 2);
    wsum += __shfl_xor(wsum, 2);
    if (h == 0) {
        float2 d2 = dx[n];
        float dn = d2.x;
        float base0 = dn * acc + dn * d2.y;     // + dn^2 * x[n]
        db0[n] = make_float2(dn, base0);
        s1v[n] = dn * wsum + dn * dn;
    }
}

// layer 1: 2 threads/node edge phase (q[16] partials, 4 gathers in flight),
// then 16-lane epilogue: v2 = q@M + c*m2 + cb1 ; h2hat = dinv*(relu(v2)@lw1 + lb1)
__global__ __launch_bounds__(256) void agg1_kernel(const u64* __restrict__ sorted,
                                                   const int* __restrict__ nodeoff,
                                                   const float2* __restrict__ db0,
                                                   const float* __restrict__ s1v,
                                                   const float* __restrict__ cw0,
                                                   const float* __restrict__ cb0,
                                                   const float* __restrict__ lw0,
                                                   const float* __restrict__ lb0,
                                                   const float* __restrict__ cwr0,
                                                   const float* __restrict__ cb1,
                                                   const float* __restrict__ lw1,
                                                   const float* __restrict__ lb1,
                                                   float* __restrict__ h2hat) {
    __shared__ float sq[128 * 20];   // per node: q[16], c, dn, pad2  (10 KB)
    __shared__ float sa2[256];       // wave-local relu scratch
    __shared__ float sM[256];        // M = lw0 @ cwr0
    __shared__ float sm2[16];        // m2 = lb0 @ cwr0
    int t = threadIdx.x;
    int j = t & 15;
    {   // fused prep
        int kk = t >> 4;
        float accM = 0.f;
#pragma unroll
        for (int xx = 0; xx < 16; ++xx) accM += lw0[kk * 16 + xx] * cwr0[xx * 16 + j];
        sM[t] = accM;
        if (t < 16) {
            float a2 = 0.f;
#pragma unroll
            for (int xx = 0; xx < 16; ++xx) a2 += lb0[xx] * cwr0[xx * 16 + t];
            sm2[t] = a2;
        }
    }
    __syncthreads();
    float cwr[16], cbr[16];
#pragma unroll
    for (int k = 0; k < 16; ++k) { cwr[k] = cw0[k]; cbr[k] = cb0[k]; }

    int n = blockIdx.x * 128 + (t >> 1);
    int h = t & 1;
    float q[16];
#pragma unroll
    for (int k = 0; k < 16; ++k) q[k] = 0.f;
    if (n < N_NODES) {
        int e0 = nodeoff[n];
        int e1 = (n < N_NODES - 1) ? nodeoff[n + 1] : N_EDGES;
        int i = e0 + h;
        for (; i + 6 < e1; i += 8) {
            u64 en0 = sorted[i],     en1 = sorted[i + 2];
            u64 en2 = sorted[i + 4], en3 = sorted[i + 6];
            float2 g0 = db0[(int)(en0 & 0x3ffffu)];
            float2 g1 = db0[(int)(en1 & 0x3ffffu)];
            float2 g2 = db0[(int)(en2 & 0x3ffffu)];
            float2 g3 = db0[(int)(en3 & 0x3ffffu)];
            float a0 = __uint_as_float((unsigned)(en0 >> 32)) * g0.x;  // ea*dinv[s]
            float a1 = __uint_as_float((unsigned)(en1 >> 32)) * g1.x;
            float a2 = __uint_as_float((unsigned)(en2 >> 32)) * g2.x;
            float a3 = __uint_as_float((unsigned)(en3 >> 32)) * g3.x;
#pragma unroll
            for (int k = 0; k < 16; ++k)
                q[k] += a0 * fmaxf(g0.y * cwr[k] + cbr[k], 0.f)
                      + a1 * fmaxf(g1.y * cwr[k] + cbr[k], 0.f)
                      + a2 * fmaxf(g2.y * cwr[k] + cbr[k], 0.f)
                      + a3 * fmaxf(g3.y * cwr[k] + cbr[k], 0.f);
        }
        for (; i < e1; i += 2) {
            u64 en = sorted[i];
            float2 g = db0[(int)(en & 0x3ffffu)];
            float a = __uint_as_float((unsigned)(en >> 32)) * g.x;
#pragma unroll
            for (int k = 0; k < 16; ++k)
                q[k] += a * fmaxf(g.y * cwr[k] + cbr[k], 0.f);
        }
    }
    // combine halves (lane pairs 2k/2k+1, in-wave)
#pragma unroll
    for (int k = 0; k < 16; ++k) q[k] += __shfl_xor(q[k], 1);
    float dn = 0.f, cval = 0.f;
    if (n < N_NODES) {
        float2 self = db0[n];
        dn = self.x;
        float ds = dn * dn;
#pragma unroll
        for (int k = 0; k < 16; ++k)
            q[k] = dn * q[k] + ds * fmaxf(self.y * cwr[k] + cbr[k], 0.f);
        cval = s1v[n];
    }
    if (h == 0) {
        float* row = sq + (t >> 1) * 20;
#pragma unroll
        for (int k = 0; k < 16; k += 4)
            *(float4*)(row + k) = make_float4(q[k], q[k + 1], q[k + 2], q[k + 3]);
        row[16] = cval;
        row[17] = dn;
    }
    __syncthreads();
    // epilogue weights loaded post edge phase (lower edge-phase VGPR)
    float Mc[16], W1c[16];
#pragma unroll
    for (int k = 0; k < 16; ++k) { Mc[k] = sM[k * 16 + j]; W1c[k] = lw1[k * 16 + j]; }
    float m2j = sm2[j], cb1j = cb1[j], lb1j = lb1[j];
    int g = t >> 4;
    float* ar = sa2 + g * 16;
    for (int it = 0; it < 8; ++it) {
        int nl = g * 8 + it;
        const float* r = sq + nl * 20;
        float4 q0 = *(const float4*)(r);
        float4 q1 = *(const float4*)(r + 4);
        float4 q2 = *(const float4*)(r + 8);
        float4 q3 = *(const float4*)(r + 12);
        float c2 = r[16], dn2 = r[17];
        float v2 = c2 * m2j + cb1j;
        v2 += q0.x * Mc[0] + q0.y * Mc[1] + q0.z * Mc[2] + q0.w * Mc[3];
        v2 += q1.x * Mc[4] + q1.y * Mc[5] + q1.z * Mc[6] + q1.w * Mc[7];
        v2 += q2.x * Mc[8] + q2.y * Mc[9] + q2.z * Mc[10] + q2.w * Mc[11];
        v2 += q3.x * Mc[12] + q3.y * Mc[13] + q3.z * Mc[14] + q3.w * Mc[15];
        ar[j] = fmaxf(v2, 0.f);          // wave-local
        float o = lb1j;
#pragma unroll
        for (int k = 0; k < 16; ++k) o += ar[k] * W1c[k];
        int n2 = blockIdx.x * 128 + nl;
        if (n2 < N_NODES) h2hat[(size_t)n2 * 16 + j] = dn2 * o;
    }
}

// layer 2: PINNED at random-64B-line fetch ceiling (67.5 µs across 3 configs,
// R9/R12/R14; R2-fusion attempt regressed it to 94 via VGPR 36->48, occupancy
// 60->41; R4 misaligned h2hat base (8 mod 64) regressed it to 85 via line-
// straddling row gathers, FETCH 182->261 MB. Keep h2hat 64B-aligned. Do not
// add state to this kernel.)
__global__ __launch_bounds__(256) void agg2_kernel(const u64* __restrict__ sorted,
                                                   const int* __restrict__ nodeoff,
                                                   const float* __restrict__ h2hat,
                                                   const float* __restrict__ dinv,
                                                   const float* __restrict__ cwr1,
                                                   const float* __restrict__ cb2,
                                                   const float* __restrict__ lw2,
                                                   const float* __restrict__ lb2,
                                                   float* __restrict__ h3) {
    __shared__ float sz[256];   // per (group, j) — wave-local roundtrip
    int t = threadIdx.x, j = t & 15, g = t >> 4;
    float W1c[16], W2c[16];
#pragma unroll
    for (int k = 0; k < 16; ++k) { W1c[k] = cwr1[k * 16 + j]; W2c[k] = lw2[k * 16 + j]; }
    float cb2j = cb2[j], lb2j = lb2[j];
    const float* zr = sz + g * 16;
    int nbase = blockIdx.x * 64 + g * 4;     // 3125 * 64 = 200000 exactly
#pragma unroll
    for (int it = 0; it < 4; ++it) {
        int n = nbase + it;
        int e0 = nodeoff[n];
        int e1 = (n < N_NODES - 1) ? nodeoff[n + 1] : N_EDGES;
        float q = 0.f;
        int i = e0;
        for (; i + 8 <= e1; i += 8) {
            u64 en0 = sorted[i],     en1 = sorted[i + 1], en2 = sorted[i + 2], en3 = sorted[i + 3];
            u64 en4 = sorted[i + 4], en5 = sorted[i + 5], en6 = sorted[i + 6], en7 = sorted[i + 7];
            float g0 = h2hat[(size_t)(en0 & 0x3ffffu) * 16 + j];
            float g1 = h2hat[(size_t)(en1 & 0x3ffffu) * 16 + j];
            float g2 = h2hat[(size_t)(en2 & 0x3ffffu) * 16 + j];
            float g3 = h2hat[(size_t)(en3 & 0x3ffffu) * 16 + j];
            float g4 = h2hat[(size_t)(en4 & 0x3ffffu) * 16 + j];
            float g5 = h2hat[(size_t)(en5 & 0x3ffffu) * 16 + j];
            float g6 = h2hat[(size_t)(en6 & 0x3ffffu) * 16 + j];
            float g7 = h2hat[(size_t)(en7 & 0x3ffffu) * 16 + j];
            q += __uint_as_float((unsigned)(en0 >> 32)) * g0
               + __uint_as_float((unsigned)(en1 >> 32)) * g1
               + __uint_as_float((unsigned)(en2 >> 32)) * g2
               + __uint_as_float((unsigned)(en3 >> 32)) * g3
               + __uint_as_float((unsigned)(en4 >> 32)) * g4
               + __uint_as_float((unsigned)(en5 >> 32)) * g5
               + __uint_as_float((unsigned)(en6 >> 32)) * g6
               + __uint_as_float((unsigned)(en7 >> 32)) * g7;
        }
        for (; i < e1; ++i) {
            u64 en = sorted[i];
            q += __uint_as_float((unsigned)(en >> 32)) * h2hat[(size_t)(en & 0x3ffffu) * 16 + j];
        }
        float dn = dinv[n];
        float z = dn * (q + h2hat[(size_t)n * 16 + j]);   // + dn^2 * h2[n]
        sz[t] = z;                                        // wave-local
        float v = cb2j;
#pragma unroll
        for (int k = 0; k < 16; ++k) v += zr[k] * W1c[k];
        float a = fmaxf(v, 0.f);
        sz[t] = a;                                        // wave-local overwrite
        float o = lb2j;
#pragma unroll
        for (int k = 0; k < 16; ++k) o += zr[k] * W2c[k];
        h3[(size_t)n * 16 + j] = o;
    }
}

// fused attention-pool + final MLP: one 64-thread wave per graph.
__global__ __launch_bounds__(64) void poolfinal_kernel(const float* __restrict__ h3,
                                                       const int* __restrict__ batch,
                                                       const float* __restrict__ w1,
                                                       const float* __restrict__ b1,
                                                       const float* __restrict__ w2,
                                                       const float* __restrict__ b2,
                                                       const float* __restrict__ w3,
                                                       const float* __restrict__ b3,
                                                       float* __restrict__ out) {
    int g = blockIdx.x;
    int t = threadIdx.x;
    int j = t & 15, sg = t >> 4;
    __shared__ int range[2];
    if (t < 2) {
        int target = g + t;          // lower_bound(batch, g) / lower_bound(batch, g+1)
        int lo = 0, hi = N_NODES;
        while (lo < hi) {
            int mid = (lo + hi) >> 1;
            if (batch[mid] < target) lo = mid + 1; else hi = mid;
        }
        range[t] = lo;
    }
    __syncthreads();
    int n0 = range[0], n1 = range[1];
    float accn = 0.f, accd = 0.f;
    for (int n = n0 + sg; n < n1; n += 4) {
        float v = h3[(size_t)n * 16 + j];
        float e = __expf(ALPHA_ * v);
        accn += v * e;
        accd += e;
    }
    accn += __shfl_xor(accn, 16);
    accd += __shfl_xor(accd, 16);
    accn += __shfl_xor(accn, 32);
    accd += __shfl_xor(accd, 32);
    __shared__ float sp[16], st1[16], st2[16];
    if (t < 16) sp[j] = (accd > 0.f) ? accn / accd : 0.f;
    __syncthreads();
    if (t < 16) {
        float acc = b1[j];
#pragma unroll
        for (int k = 0; k < 16; ++k) acc += sp[k] * w1[k * 16 + j];
        st1[j] = fmaxf(acc, 0.f);
    }
    __syncthreads();
    if (t < 16) {
        float acc = b2[j];
#pragma unroll
        for (int k = 0; k < 16; ++k) acc += st1[k] * w2[k * 16 + j];
        st2[j] = fmaxf(acc, 0.f);
    }
    __syncthreads();
    if (t == 0) {
        float o = b3[0];
#pragma unroll
        for (int k = 0; k < 16; ++k) o += st2[k] * w3[k];
        out[g] = o;
    }
}

extern "C" void kernel_launch(void* const* d_in, const int* in_sizes, int n_in,
                              void* d_out, int out_size, void* d_ws, size_t ws_size,
                              hipStream_t stream) {
    const float* x   = (const float*)d_in[0];
    const int*   ei  = (const int*)d_in[1];
    const int*   src = ei;
    const int*   dst = ei + N_EDGES;
    const int*   batch = (const int*)d_in[2];
    const float* ea  = (const float*)d_in[3];
    const float* cw0 = (const float*)d_in[4];
    const float* cwr = (const float*)d_in[5];
    const float* cb  = (const float*)d_in[6];
    const float* lw  = (const float*)d_in[7];
    const float* lb  = (const float*)d_in[8];
    const float* w1  = (const float*)d_in[9];
    const float* b1  = (const float*)d_in[10];
    const float* w2  = (const float*)d_in[11];
    const float* b2  = (const float*)d_in[12];
    const float* w3  = (const float*)d_in[13];
    const float* b3  = (const float*)d_in[14];
    float* out = (float*)d_out;

    // workspace layout (4-byte units) — ALL segment bases multiple of 64 floats
    // (256 B) so 64 B-row structures (h2hat/h3) never straddle cache lines.
    float* ws      = (float*)d_ws;
    float* dinv    = ws;                                   // 200000  (0)
    float* s1v     = ws + 200000;                          // 200000
    float2* db0    = (float2*)(ws + 400000);               // 400000 floats
    int*   bstart  = (int*)(ws + 800000);                  // 392 -> pad 448
    int*   nodeoff = (int*)(ws + 800448);                  // 200010 -> pad 200064
    int*   gcursor = (int*)(ws + 1000512);                 // 392 -> pad 448
    float2* dx     = (float2*)(ws + 1000960);              // 400000 floats
    u64* bucketedP = (u64*)(ws + 1400960);                 // 391*9216 u64 = 7206912 floats
    u64* sorted    = (u64*)(ws + 8607872);                 // 3.2M u64 = 6400000 floats
    float* h2hat   = (float*)bucketedP;                    // alias: free after sortd; 64B-aligned
    float* h3      = h2hat + (size_t)N_NODES * HD;         // alias; 64B-aligned

    hipMemsetAsync(gcursor, 0, (size_t)392 * sizeof(int), stream);

    // single-pass bucketing (global atomic reservation, padded buckets)
    bucket_kernel<<<NBLKA, 512, 0, stream>>>(src, dst, ea, gcursor, bucketedP);
    // compact bucket starts
    scanB_kernel<<<1, 256, 0, stream>>>(gcursor, bstart);
    // in-bucket counting sort + dinv/dx
    sortd_kernel<<<NBUCK, 1024, 0, stream>>>(bucketedP, gcursor, bstart, x, sorted, nodeoff, dinv, dx);

    // layer 0 (4 threads/node) -> db0={dinv,base0}, s1
    agg0_kernel<<<3125, 256, 0, stream>>>(sorted, nodeoff, dx, db0, s1v);
    // layer 1 (2 threads/node, 4-wide MLP + fused prep + 2-stage epilogue) -> h2hat
    agg1_kernel<<<1563, 256, 0, stream>>>(sorted, nodeoff, db0, s1v,
                                          cw0, cb, lw, lb,
                                          cwr, cb + 16, lw + 256, lb + 16, h2hat);
    // layer 2 (unroll-8 gathers) -> h3
    agg2_kernel<<<3125, 256, 0, stream>>>(sorted, nodeoff, h2hat, dinv,
                                          cwr + 256, cb + 32, lw + 512, lb + 32, h3);

    // fused attention pooling + final MLP (one wave per graph)
    poolfinal_kernel<<<N_GRAPHS, 64, 0, stream>>>(h3, batch, w1, b1, w2, b2, w3, b3, out);
}